// Round 5
// baseline (3062.683 us; speedup 1.0000x reference)
//
#include <hip/hip_runtime.h>
#include <hip/hip_bf16.h>
#include <math.h>

// Problem constants
#define BB   4
#define SS   1024
#define BSR  4096          // B*S rows
#define VV   256
#define KDIM 64
#define HH   8
#define TT   4
#define EPSV 1e-3f
#define SCL  0.125f        // KD^-0.5
#define INV2048 4.8828125e-4f

typedef float f4 __attribute__((ext_vector_type(4)));
typedef short bf8 __attribute__((ext_vector_type(8)));       // 8 bf16
typedef short s4v __attribute__((ext_vector_type(4)));
typedef _Float16 h8 __attribute__((ext_vector_type(8)));     // 8 f16
typedef _Float16 h4v __attribute__((ext_vector_type(4)));

#define LDP 68             // fp32 GEMM LDS stride (floats)
#define LKS 68             // attention LDS stride (shorts/halves; 34 dwords)

__device__ __forceinline__ short f2bf(float x) {
  __hip_bfloat16 h = __float2bfloat16(x);   // RNE
  return *reinterpret_cast<short*>(&h);
}
__device__ __forceinline__ float bf2f(short h) {
  union { unsigned u; float f; } cv;
  cv.u = ((unsigned)(unsigned short)h) << 16;
  return cv.f;
}

// ---------------------------------------------------------------------------
// 64x64 fp32 GEMM core, K=256, lda fixed 256. Block = 256 threads (16x16),
// each thread owns a 4x4 microtile. acc[i][j]: row ty*4+i, col tx*4+j.
// ---------------------------------------------------------------------------
__device__ __forceinline__ void gemm_core(
    const float* __restrict__ A, const float* __restrict__ Bm, int ldb,
    float acc[4][4], float (*As)[LDP], float (*Bs)[LDP])
{
  const int tid = threadIdx.x;
  const int tx = tid & 15, ty = tid >> 4;
#pragma unroll
  for (int i = 0; i < 4; i++)
#pragma unroll
    for (int j = 0; j < 4; j++) acc[i][j] = 0.f;

  for (int k0 = 0; k0 < 256; k0 += 16) {
#pragma unroll
    for (int l = 0; l < 4; l++) {
      int e = tid + l * 256;
      int r = e >> 4, kk = e & 15;
      As[kk][r] = A[r * 256 + k0 + kk];
      int rb = e >> 6, nn = e & 63;
      Bs[rb][nn] = Bm[(k0 + rb) * ldb + nn];
    }
    __syncthreads();
#pragma unroll
    for (int kk = 0; kk < 16; kk++) {
      f4 av = *(const f4*)&As[kk][ty * 4];
      f4 bv = *(const f4*)&Bs[kk][tx * 4];
#pragma unroll
      for (int i = 0; i < 4; i++)
#pragma unroll
        for (int j = 0; j < 4; j++)
          acc[i][j] += av[i] * bv[j];
    }
    __syncthreads();
  }
}

// ---------------------------------------------------------------------------
// net0 = x @ W_in, broadcast into all H head slots of `net`
// ---------------------------------------------------------------------------
__global__ __launch_bounds__(256) void k_in_dense(
    const float* __restrict__ x, const float* __restrict__ Win,
    float* __restrict__ net)
{
  __shared__ __align__(16) float As[16][LDP];
  __shared__ __align__(16) float Bs[16][LDP];
  const int mt = blockIdx.x, nt = blockIdx.y;
  float acc[4][4];
  gemm_core(x + mt * 64 * 256, Win + nt * 64, 256, acc, As, Bs);
  const int tx = threadIdx.x & 15, ty = threadIdx.x >> 4;
#pragma unroll
  for (int i = 0; i < 4; i++) {
    f4 v;
#pragma unroll
    for (int j = 0; j < 4; j++) v[j] = acc[i][j];
    int row = mt * 64 + ty * 4 + i;
    int col = nt * 64 + tx * 4;
    for (int h = 0; h < HH; h++)
      *(f4*)&net[(size_t)h * 1048576 + row * 256 + col] = v;
  }
}

// ---------------------------------------------------------------------------
// Fused QKV. Epilogues for the MFMA attention consumer:
//   qh/ql, kh/kl: f16 hi + scaled-lo (x2048), row-major [h][BS][64]
//   vth/vtl: bf16 hi/lo split, transposed [h*4+b][vcol(256)][s(1024)]
// grid: (64 m-tiles, 6 n-tiles [0:q 1:k 2..5:v], 8 heads)
// ---------------------------------------------------------------------------
__global__ __launch_bounds__(256) void k_qkv(
    const float* __restrict__ net,
    const float* __restrict__ Wq, const float* __restrict__ Wk,
    const float* __restrict__ Wv,
    _Float16* __restrict__ qhb, _Float16* __restrict__ qlb,
    _Float16* __restrict__ khb, _Float16* __restrict__ klb,
    short* __restrict__ vth, short* __restrict__ vtl,
    int t)
{
  __shared__ __align__(16) float As[16][LDP];
  __shared__ __align__(16) float Bs[16][LDP];
  const int mt = blockIdx.x, nt = blockIdx.y, h = blockIdx.z;
  const float* A = net + (size_t)h * 1048576 + mt * 64 * 256;
  const float* Bm; int ldb;
  if (nt == 0)      { Bm = Wq + (size_t)(h * TT + t) * VV * KDIM; ldb = KDIM; }
  else if (nt == 1) { Bm = Wk + (size_t)(h * TT + t) * VV * KDIM; ldb = KDIM; }
  else              { Bm = Wv + (size_t)(h * TT + t) * VV * VV + (nt - 2) * 64; ldb = VV; }
  float acc[4][4];
  gemm_core(A, Bm, ldb, acc, As, Bs);
  const int tx = threadIdx.x & 15, ty = threadIdx.x >> 4;

  if (nt <= 1) {
    _Float16* hb = (nt == 0) ? qhb : khb;
    _Float16* lb = (nt == 0) ? qlb : klb;
#pragma unroll
    for (int i = 0; i < 4; i++) {
      int row = mt * 64 + ty * 4 + i;
      h4v hv, lv;
#pragma unroll
      for (int j = 0; j < 4; j++) {
        float q = acc[i][j];
        _Float16 hi = (_Float16)q;
        hv[j] = hi;
        lv[j] = (_Float16)((q - (float)hi) * 2048.f);
      }
      size_t base = ((size_t)h * 4096 + row) * 64 + tx * 4;
      *(h4v*)&hb[base] = hv;
      *(h4v*)&lb[base] = lv;
    }
  } else {
    const int c0 = (nt - 2) * 64;
#pragma unroll
    for (int i = 0; i < 4; i++) {
      int row = mt * 64 + ty * 4 + i;
      int b_ = row >> 10, sI = row & 1023;
#pragma unroll
      for (int j = 0; j < 4; j++) {
        float v = acc[i][j];
        short hi = f2bf(v);
        short lo = f2bf(v - bf2f(hi));
        size_t idx = ((size_t)(h * 4 + b_) * 256 + c0 + tx * 4 + j) * 1024 + sI;
        vth[idx] = hi;
        vtl[idx] = lo;
      }
    }
  }
}

// ---------------------------------------------------------------------------
// tmp = net + relu(net @ Wd[h][t]), FUSED BN stats (sum/sumsq per channel).
// grid: (64, 4, 8)
// ---------------------------------------------------------------------------
__global__ __launch_bounds__(256) void k_dense(
    const float* __restrict__ net, const float* __restrict__ Wd,
    float* __restrict__ tmp, float* __restrict__ stats, int t)
{
  __shared__ __align__(16) float As[16][LDP];
  __shared__ __align__(16) float Bs[16][LDP];
  const int mt = blockIdx.x, nt = blockIdx.y, h = blockIdx.z;
  const float* A = net + (size_t)h * 1048576 + mt * 64 * 256;
  const float* Bm = Wd + (size_t)(h * TT + t) * VV * VV + nt * 64;
  float acc[4][4];
  gemm_core(A, Bm, 256, acc, As, Bs);
  const int tid = threadIdx.x, tx = tid & 15, ty = tid >> 4;

  float cs[4] = {0.f, 0.f, 0.f, 0.f}, cq[4] = {0.f, 0.f, 0.f, 0.f};
#pragma unroll
  for (int i = 0; i < 4; i++) {
    int row = mt * 64 + ty * 4 + i;
    int col = nt * 64 + tx * 4;
    f4 nv = *(const f4*)&net[(size_t)h * 1048576 + row * 256 + col];
    f4 ov;
#pragma unroll
    for (int j = 0; j < 4; j++) {
      float y = nv[j] + fmaxf(acc[i][j], 0.f);
      ov[j] = y;
      cs[j] += y;
      cq[j] += y * y;
    }
    *(f4*)&tmp[(size_t)h * 1048576 + row * 256 + col] = ov;
  }
  // reduce over the wave's 4 ty values (lane bits 4,5), then atomics
#pragma unroll
  for (int j = 0; j < 4; j++) {
    cs[j] += __shfl_xor(cs[j], 16, 64); cs[j] += __shfl_xor(cs[j], 32, 64);
    cq[j] += __shfl_xor(cq[j], 16, 64); cq[j] += __shfl_xor(cq[j], 32, 64);
  }
  if (((tid >> 4) & 3) == 0) {
#pragma unroll
    for (int j = 0; j < 4; j++) {
      int c = nt * 64 + tx * 4 + j;
      atomicAdd(&stats[(h * 256 + c) * 2], cs[j]);
      atomicAdd(&stats[(h * 256 + c) * 2 + 1], cq[j]);
    }
  }
}

// ---------------------------------------------------------------------------
// MFMA flash attention, exact-split f16 S-phase + proven bf16-split PV.
// S = Qh Kh^T + 2^-11 (Qh Kl'^T + Ql' Kh^T)  -- only dropped term ~2^-22.
// Epilogue: y = net + O/l -> tmp, fused BN stats.
// Block = 256 = 4 waves; wave w owns q-rows wv*16.. ; 64 q-rows/block.
// MFMA maps (verified R4): A[m=ln][k=quad*8+j], B[n=ln][k=quad*8+j],
// C/D row=quad*4+r, col=ln.
// grid: (16 q-tiles, 4 batch, 8 heads)
// ---------------------------------------------------------------------------
__global__ __launch_bounds__(256, 3) void k_attn(
    const _Float16* __restrict__ qhb, const _Float16* __restrict__ qlb,
    const _Float16* __restrict__ khb, const _Float16* __restrict__ klb,
    const short* __restrict__ vth, const short* __restrict__ vtl,
    const float* __restrict__ net, float* __restrict__ tmp,
    float* __restrict__ stats)
{
  // Overlaid LDS, 52,224 B total:
  //   [0, 17408): Kh+Kl during S-phase  OR  V hi-chunk region start
  //   V chunk (128 vcols x 68 x 2 planes) = [0, 34816)  (time-disjoint w/ K)
  //   P planes = [34816, 52224)
  __shared__ __align__(16) char smem[52224];
  _Float16 (*Kh)[LKS] = (_Float16(*)[LKS])(smem);           // 64 x 68 h
  _Float16 (*Kl)[LKS] = (_Float16(*)[LKS])(smem + 8704);    // 64 x 68 h
  short (*Vh)[LKS] = (short(*)[LKS])(smem);                 // 128 x 68 s
  short (*Vl)[LKS] = (short(*)[LKS])(smem + 17408);         // 128 x 68 s
  short (*Ph)[LKS] = (short(*)[LKS])(smem + 34816);         // 64 x 68 s
  short (*Pl)[LKS] = (short(*)[LKS])(smem + 43520);         // 64 x 68 s

  const int qt = blockIdx.x, b = blockIdx.y, h = blockIdx.z;
  const int tid = threadIdx.x, wv = tid >> 6, lane = tid & 63;
  const int ln = lane & 15, quad = lane >> 4;

  // Q fragments once from global (A-layout, 16B contiguous per lane)
  const int qrow = qt * 64 + wv * 16 + ln;
  const size_t qoff = ((size_t)h * 4096 + b * 1024 + qrow) * 64;
  const h8 qh0 = *(const h8*)(qhb + qoff + quad * 8);
  const h8 qh1 = *(const h8*)(qhb + qoff + 32 + quad * 8);
  const h8 ql0 = *(const h8*)(qlb + qoff + quad * 8);
  const h8 ql1 = *(const h8*)(qlb + qoff + 32 + quad * 8);

  const _Float16* khg = khb + ((size_t)h * 4096 + b * 1024) * 64;
  const _Float16* klg = klb + ((size_t)h * 4096 + b * 1024) * 64;
  const short* vhg = vth + (size_t)(h * 4 + b) * 262144;   // [256 vcol][1024 s]
  const short* vlg = vtl + (size_t)(h * 4 + b) * 262144;

  f4 O[16];
#pragma unroll
  for (int nt = 0; nt < 16; nt++) O[nt] = (f4){0.f, 0.f, 0.f, 0.f};
  float m[4] = {-1e30f, -1e30f, -1e30f, -1e30f};
  float l[4] = {0.f, 0.f, 0.f, 0.f};

  for (int kt = 0; kt < 16; kt++) {
    // stage K hi/lo tile 64x64 (one 16B load per thread per 2 units)
#pragma unroll
    for (int i = 0; i < 2; i++) {
      int e = tid + i * 256;
      int kr = e >> 3, fc = e & 7;
      *(h8*)&Kh[kr][fc * 8] = *(const h8*)&khg[(kt * 64 + kr) * 64 + fc * 8];
      *(h8*)&Kl[kr][fc * 8] = *(const h8*)&klg[(kt * 64 + kr) * 64 + fc * 8];
    }
    __syncthreads();   // B1

    // S-phase: 4 col-tiles of 16 keys; exact split w/ corr accumulator
    f4 s[4];
#pragma unroll
    for (int ct = 0; ct < 4; ct++) {
      h8 kh0 = *(const h8*)&Kh[ct * 16 + ln][quad * 8];
      h8 kh1 = *(const h8*)&Kh[ct * 16 + ln][32 + quad * 8];
      h8 kl0 = *(const h8*)&Kl[ct * 16 + ln][quad * 8];
      h8 kl1 = *(const h8*)&Kl[ct * 16 + ln][32 + quad * 8];
      f4 mn = (f4){0.f, 0.f, 0.f, 0.f};
      f4 cr = (f4){0.f, 0.f, 0.f, 0.f};
      mn = __builtin_amdgcn_mfma_f32_16x16x32_f16(qh0, kh0, mn, 0, 0, 0);
      mn = __builtin_amdgcn_mfma_f32_16x16x32_f16(qh1, kh1, mn, 0, 0, 0);
      cr = __builtin_amdgcn_mfma_f32_16x16x32_f16(qh0, kl0, cr, 0, 0, 0);
      cr = __builtin_amdgcn_mfma_f32_16x16x32_f16(qh1, kl1, cr, 0, 0, 0);
      cr = __builtin_amdgcn_mfma_f32_16x16x32_f16(ql0, kh0, cr, 0, 0, 0);
      cr = __builtin_amdgcn_mfma_f32_16x16x32_f16(ql1, kh1, cr, 0, 0, 0);
#pragma unroll
      for (int r = 0; r < 4; r++) s[ct][r] = (mn[r] + cr[r] * INV2048) * SCL;
    }

    // online softmax; lane's rows = quad*4+r, cols spread over ln (bits 0-3)
    float alpha[4];
#pragma unroll
    for (int r = 0; r < 4; r++) {
      float mx = fmaxf(fmaxf(s[0][r], s[1][r]), fmaxf(s[2][r], s[3][r]));
#pragma unroll
      for (int d = 1; d < 16; d <<= 1) mx = fmaxf(mx, __shfl_xor(mx, d, 64));
      float mn_ = fmaxf(m[r], mx);
      alpha[r] = __expf(m[r] - mn_);
      float ps = 0.f;
#pragma unroll
      for (int ct = 0; ct < 4; ct++) {
        float p = __expf(s[ct][r] - mn_);
        s[ct][r] = p;
        ps += p;
      }
#pragma unroll
      for (int d = 1; d < 16; d <<= 1) ps += __shfl_xor(ps, d, 64);
      l[r] = l[r] * alpha[r] + ps;
      m[r] = mn_;
    }
#pragma unroll
    for (int nt = 0; nt < 16; nt++)
#pragma unroll
      for (int r = 0; r < 4; r++) O[nt][r] *= alpha[r];

    // P hi/lo bf16 -> LDS (wave-private rows wv*16..)
#pragma unroll
    for (int r = 0; r < 4; r++)
#pragma unroll
      for (int ct = 0; ct < 4; ct++) {
        float p = s[ct][r];
        short hi = f2bf(p);
        Ph[wv * 16 + quad * 4 + r][ct * 16 + ln] = hi;
        Pl[wv * 16 + quad * 4 + r][ct * 16 + ln] = f2bf(p - bf2f(hi));
      }
    __syncthreads();   // B2: all waves done with Kh/Kl before V overlay

    bf8 ph0 = *(const bf8*)&Ph[wv * 16 + ln][quad * 8];
    bf8 ph1 = *(const bf8*)&Ph[wv * 16 + ln][32 + quad * 8];
    bf8 pl0 = *(const bf8*)&Pl[wv * 16 + ln][quad * 8];
    bf8 pl1 = *(const bf8*)&Pl[wv * 16 + ln][32 + quad * 8];

    // PV: 2 chunks of 128 vcols
    for (int c2 = 0; c2 < 2; c2++) {
#pragma unroll
      for (int i = 0; i < 4; i++) {
        int e = tid + i * 256;
        int vc = e >> 3, fc = e & 7;
        size_t g = (size_t)(c2 * 128 + vc) * 1024 + kt * 64 + fc * 8;
        *(bf8*)&Vh[vc][fc * 8] = *(const bf8*)&vhg[g];
        *(bf8*)&Vl[vc][fc * 8] = *(const bf8*)&vlg[g];
      }
      __syncthreads();  // B3
#pragma unroll
      for (int n2 = 0; n2 < 8; n2++) {
        int nt = c2 * 8 + n2;
        bf8 vh0 = *(const bf8*)&Vh[n2 * 16 + ln][quad * 8];
        bf8 vh1 = *(const bf8*)&Vh[n2 * 16 + ln][32 + quad * 8];
        bf8 vl0 = *(const bf8*)&Vl[n2 * 16 + ln][quad * 8];
        bf8 vl1 = *(const bf8*)&Vl[n2 * 16 + ln][32 + quad * 8];
        O[nt] = __builtin_amdgcn_mfma_f32_16x16x32_bf16(ph0, vh0, O[nt], 0, 0, 0);
        O[nt] = __builtin_amdgcn_mfma_f32_16x16x32_bf16(ph1, vh1, O[nt], 0, 0, 0);
        O[nt] = __builtin_amdgcn_mfma_f32_16x16x32_bf16(ph0, vl0, O[nt], 0, 0, 0);
        O[nt] = __builtin_amdgcn_mfma_f32_16x16x32_bf16(ph1, vl1, O[nt], 0, 0, 0);
        O[nt] = __builtin_amdgcn_mfma_f32_16x16x32_bf16(pl0, vh0, O[nt], 0, 0, 0);
        O[nt] = __builtin_amdgcn_mfma_f32_16x16x32_bf16(pl1, vh1, O[nt], 0, 0, 0);
      }
      __syncthreads();  // B4: chunk reads done before next staging
    }
  }

  // epilogue: y = net + O/l -> tmp, plus fused BN stats
  float linv[4];
#pragma unroll
  for (int r = 0; r < 4; r++) linv[r] = 1.f / l[r];
  const size_t rbase = (size_t)h * 1048576 + (size_t)b * 262144;
#pragma unroll
  for (int nt = 0; nt < 16; nt++) {
    int c = nt * 16 + ln;
    float as = 0.f, aq = 0.f;
#pragma unroll
    for (int r = 0; r < 4; r++) {
      int row = qt * 64 + wv * 16 + quad * 4 + r;
      size_t idx = rbase + (size_t)row * 256 + c;
      float y = net[idx] + O[nt][r] * linv[r];
      tmp[idx] = y;
      as += y;
      aq += y * y;
    }
    as += __shfl_xor(as, 16, 64); as += __shfl_xor(as, 32, 64);
    aq += __shfl_xor(aq, 16, 64); aq += __shfl_xor(aq, 32, 64);
    if (quad == 0) {
      atomicAdd(&stats[(h * 256 + c) * 2], as);
      atomicAdd(&stats[(h * 256 + c) * 2 + 1], aq);
    }
  }
}

// ---------------------------------------------------------------------------
// BN apply: dst = (y - mean) * rsqrt(var+eps) * gamma + beta.
// transposed=1 writes d_out in [B,S,H,V] layout.
// ---------------------------------------------------------------------------
__global__ __launch_bounds__(256) void k_bnapply(
    const float* __restrict__ a,
    const float* __restrict__ stats,
    const float* __restrict__ gamma, const float* __restrict__ beta,
    float* __restrict__ dst, int t, int transposed)
{
  const int h = blockIdx.y, r0 = blockIdx.x * 64, c = threadIdx.x;
  float s  = stats[(h * 256 + c) * 2];
  float s2 = stats[(h * 256 + c) * 2 + 1];
  float mean = s * (1.f / 4096.f);
  float var  = s2 * (1.f / 4096.f) - mean * mean;
  float inv  = rsqrtf(var + EPSV);
  float g  = gamma[(h * TT + t) * 256 + c] * inv;
  float bt = beta[(h * TT + t) * 256 + c];
  const float* pa = a + (size_t)h * 1048576 + r0 * 256 + c;
  for (int r = 0; r < 64; r++) {
    float y = pa[r * 256];
    float o = (y - mean) * g + bt;
    int rg = r0 + r;
    if (transposed) dst[((size_t)rg * HH + h) * 256 + c] = o;
    else            dst[(size_t)h * 1048576 + rg * 256 + c] = o;
  }
}

// ---------------------------------------------------------------------------
extern "C" void kernel_launch(void* const* d_in, const int* in_sizes, int n_in,
                              void* d_out, int out_size, void* d_ws, size_t ws_size,
                              hipStream_t stream)
{
  const float* x   = (const float*)d_in[0];
  const float* Win = (const float*)d_in[1];
  const float* Wq  = (const float*)d_in[2];
  const float* Wk  = (const float*)d_in[3];
  const float* Wv  = (const float*)d_in[4];
  const float* Wd  = (const float*)d_in[5];
  const float* g1  = (const float*)d_in[6];
  const float* b1  = (const float*)d_in[7];
  const float* g2  = (const float*)d_in[8];
  const float* b2  = (const float*)d_in[9];
  float* out = (float*)d_out;
  float* ws  = (float*)d_ws;

  float* net   = ws;                        // H*BS*V fp32      = 8,388,608 f
  float* tmp   = net + 8388608;             // H*BS*V fp32      = 8,388,608 f
  float* stats = tmp + 8388608;             // 8 phases * H*V*2 =    32,768 f
  _Float16* qhb = (_Float16*)(stats + 32768);   // H*BS*64      = 2,097,152 h
  _Float16* qlb = qhb + 2097152;
  _Float16* khb = qlb + 2097152;
  _Float16* klb = khb + 2097152;
  short* vth = (short*)(klb + 2097152);     // H*B*V*S bf16 hi  = 8,388,608 s
  short* vtl = vth + 8388608;               // H*B*V*S bf16 lo  = 8,388,608 s

  hipMemsetAsync(stats, 0, 8 * HH * VV * 2 * sizeof(float), stream);

  k_in_dense<<<dim3(64, 4), 256, 0, stream>>>(x, Win, net);

  for (int t = 0; t < TT; t++) {
    float* st1 = stats + (t * 2 + 0) * HH * VV * 2;
    float* st2 = stats + (t * 2 + 1) * HH * VV * 2;

    k_qkv<<<dim3(64, 6, 8), 256, 0, stream>>>(net, Wq, Wk, Wv,
                                              qhb, qlb, khb, klb, vth, vtl, t);
    k_attn<<<dim3(16, 4, 8), 256, 0, stream>>>(qhb, qlb, khb, klb, vth, vtl,
                                               net, tmp, st1);
    k_bnapply<<<dim3(64, 8), 256, 0, stream>>>(tmp, st1, g1, b1, net, t, 0);

    k_dense<<<dim3(64, 4, 8), 256, 0, stream>>>(net, Wd, tmp, st2, t);

    if (t < TT - 1)
      k_bnapply<<<dim3(64, 8), 256, 0, stream>>>(tmp, st2, g2, b2, net, t, 0);
    else
      k_bnapply<<<dim3(64, 8), 256, 0, stream>>>(tmp, st2, g2, b2, out, t, 1);
  }
}

// Round 6
// 1593.499 us; speedup vs baseline: 1.9220x; 1.9220x over previous
//
#include <hip/hip_runtime.h>
#include <hip/hip_bf16.h>
#include <math.h>

// Problem constants
#define BB   4
#define SS   1024
#define VV   256
#define KDIM 64
#define HH   8
#define TT   4
#define EPSV 1e-3f
#define SCL  0.125f        // KD^-0.5
#define INV2048 4.8828125e-4f

typedef float f4 __attribute__((ext_vector_type(4)));
typedef short bf8 __attribute__((ext_vector_type(8)));       // 8 bf16
typedef _Float16 h8 __attribute__((ext_vector_type(8)));     // 8 f16
typedef _Float16 h4 __attribute__((ext_vector_type(4)));

#define LDP 68   // fp32 GEMM LDS stride (floats)
#define LQP 68   // fp32 attention LDS stride (floats)
#define LKP 72   // R4 attention bf16 stride (shorts)
#define LHS 68   // split-f16 GEMM LDS stride (halves; 34 dwords -> 2-way, free)

__device__ __forceinline__ short f2bf(float x) {
  __hip_bfloat16 h = __float2bfloat16(x);   // RNE
  return *reinterpret_cast<short*>(&h);
}
__device__ __forceinline__ float bf2f(short h) {
  union { unsigned u; float f; } cv;
  cv.u = ((unsigned)(unsigned short)h) << 16;
  return cv.f;
}

// ---------------------------------------------------------------------------
// fp32 GEMM core (R4, proven) — used only by k_in_dense (1 dispatch).
// ---------------------------------------------------------------------------
__device__ __forceinline__ void gemm_core(
    const float* __restrict__ A, const float* __restrict__ Bm, int ldb,
    float acc[4][4], float (*As)[LDP], float (*Bs)[LDP])
{
  const int tid = threadIdx.x;
  const int tx = tid & 15, ty = tid >> 4;
#pragma unroll
  for (int i = 0; i < 4; i++)
#pragma unroll
    for (int j = 0; j < 4; j++) acc[i][j] = 0.f;

  for (int k0 = 0; k0 < 256; k0 += 16) {
#pragma unroll
    for (int l = 0; l < 4; l++) {
      int e = tid + l * 256;
      int r = e >> 4, kk = e & 15;
      As[kk][r] = A[r * 256 + k0 + kk];
      int rb = e >> 6, nn = e & 63;
      Bs[rb][nn] = Bm[(k0 + rb) * ldb + nn];
    }
    __syncthreads();
#pragma unroll
    for (int kk = 0; kk < 16; kk++) {
      f4 av = *(const f4*)&As[kk][ty * 4];
      f4 bv = *(const f4*)&Bs[kk][tx * 4];
#pragma unroll
      for (int i = 0; i < 4; i++)
#pragma unroll
        for (int j = 0; j < 4; j++)
          acc[i][j] += av[i] * bv[j];
    }
    __syncthreads();
  }
}

// ---------------------------------------------------------------------------
// net0 = x @ W_in, broadcast into all H head slots (R4 verbatim)
// ---------------------------------------------------------------------------
__global__ __launch_bounds__(256) void k_in_dense(
    const float* __restrict__ x, const float* __restrict__ Win,
    float* __restrict__ net)
{
  __shared__ __align__(16) float As[16][LDP];
  __shared__ __align__(16) float Bs[16][LDP];
  const int mt = blockIdx.x, nt = blockIdx.y;
  float acc[4][4];
  gemm_core(x + mt * 64 * 256, Win + nt * 64, 256, acc, As, Bs);
  const int tx = threadIdx.x & 15, ty = threadIdx.x >> 4;
#pragma unroll
  for (int i = 0; i < 4; i++) {
    f4 v;
#pragma unroll
    for (int j = 0; j < 4; j++) v[j] = acc[i][j];
    int row = mt * 64 + ty * 4 + i;
    int col = nt * 64 + tx * 4;
    for (int h = 0; h < HH; h++)
      *(f4*)&net[(size_t)h * 1048576 + row * 256 + col] = v;
  }
}

// ---------------------------------------------------------------------------
// Weight prep (per t): transpose + split into f16 hi/lo, layout [n][k(256)].
// Regions in halves: q: h*16384 ; k: 131072+h*16384 ; v: 262144+h*65536 ;
// d: 786432+h*65536. grid (10, 4 kb, 8 h): x 0=q,1=k,2..5=v,6..9=d.
// ---------------------------------------------------------------------------
__global__ __launch_bounds__(256) void k_prep(
    const float* __restrict__ Wq, const float* __restrict__ Wk,
    const float* __restrict__ Wv, const float* __restrict__ Wd,
    _Float16* __restrict__ oh, _Float16* __restrict__ ol, int t)
{
  __shared__ __align__(16) _Float16 Th[64][LHS];
  __shared__ __align__(16) _Float16 Tl[64][LHS];
  const int xb = blockIdx.x, kb = blockIdx.y, h = blockIdx.z;
  const int tid = threadIdx.x;
  const float* src; int N, nb; size_t dbase;
  if (xb == 0)      { src = Wq; N = 64;  nb = 0;      dbase = (size_t)h * 16384; }
  else if (xb == 1) { src = Wk; N = 64;  nb = 0;      dbase = 131072 + (size_t)h * 16384; }
  else if (xb < 6)  { src = Wv; N = 256; nb = xb - 2; dbase = 262144 + (size_t)h * 65536; }
  else              { src = Wd; N = 256; nb = xb - 6; dbase = 786432 + (size_t)h * 65536; }
  src += (size_t)(h * TT + t) * 256 * N;
  // load 64(k) x 64(n) tile coalesced, split to hi/lo in LDS
#pragma unroll
  for (int i = 0; i < 4; i++) {
    int fi = tid + i * 256;
    int r = fi >> 4, c4 = fi & 15;
    f4 w = *(const f4*)&src[(size_t)(kb * 64 + r) * N + nb * 64 + c4 * 4];
    h4 hv, lv;
#pragma unroll
    for (int j = 0; j < 4; j++) {
      _Float16 hi = (_Float16)w[j];
      hv[j] = hi;
      lv[j] = (_Float16)((w[j] - (float)hi) * 2048.f);
    }
    *(h4*)&Th[r][c4 * 4] = hv;
    *(h4*)&Tl[r][c4 * 4] = lv;
  }
  __syncthreads();
  // write transposed [n][k], coalesced along k
#pragma unroll
  for (int i = 0; i < 4; i++) {
    int fo = tid + i * 256;
    int nr = fo >> 4, k4 = fo & 15;
    h4 hv, lv;
#pragma unroll
    for (int j = 0; j < 4; j++) { hv[j] = Th[k4 * 4 + j][nr]; lv[j] = Tl[k4 * 4 + j][nr]; }
    size_t d = dbase + (size_t)(nb * 64 + nr) * 256 + kb * 64 + k4 * 4;
    *(h4*)&oh[d] = hv;
    *(h4*)&ol[d] = lv;
  }
}

// ---------------------------------------------------------------------------
// Split-f16 MFMA GEMM core: 64x64 tile, K=256 (4 chunks of 64).
// C = A@B with A fp32 (split on the fly), B prepped hi/lo [n][256].
// acc = main + corr/2048 (dropped lo*lo ~ 2^-22). Block 256 = 4 waves,
// wave wv owns n-cols [wv*16,wv*16+16). cm[mf]: rows mf*16+quad*4+r, col ln.
// ---------------------------------------------------------------------------
__device__ __forceinline__ void mm_core(
    const float* __restrict__ A,          // tile row 0, lda=256
    const _Float16* __restrict__ Bh,      // n-tile base
    const _Float16* __restrict__ Bl,
    f4 cm[4],
    _Float16 (*Ah)[LHS], _Float16 (*Al)[LHS])
{
  const int tid = threadIdx.x, wv = tid >> 6, lane = tid & 63;
  const int ln = lane & 15, quad = lane >> 4;
  f4 mn[4], cr[4];
#pragma unroll
  for (int mf = 0; mf < 4; mf++) {
    mn[mf] = (f4){0.f, 0.f, 0.f, 0.f};
    cr[mf] = (f4){0.f, 0.f, 0.f, 0.f};
  }
  const _Float16* bhp = Bh + (size_t)(wv * 16 + ln) * 256;
  const _Float16* blp = Bl + (size_t)(wv * 16 + ln) * 256;

  for (int kc = 0; kc < 4; kc++) {
    // stage A chunk 64x64: coalesced f4 loads, split, LDS h4 stores
#pragma unroll
    for (int i = 0; i < 4; i++) {
      int fi = tid + i * 256;
      int r = fi >> 4, c4 = fi & 15;
      f4 w = *(const f4*)&A[(size_t)r * 256 + kc * 64 + c4 * 4];
      h4 hv, lv;
#pragma unroll
      for (int j = 0; j < 4; j++) {
        _Float16 hi = (_Float16)w[j];
        hv[j] = hi;
        lv[j] = (_Float16)((w[j] - (float)hi) * 2048.f);
      }
      *(h4*)&Ah[r][c4 * 4] = hv;
      *(h4*)&Al[r][c4 * 4] = lv;
    }
    // B fragments straight from global (prepped, L2-hot)
    h8 bh0 = *(const h8*)&bhp[kc * 64 + quad * 8];
    h8 bh1 = *(const h8*)&bhp[kc * 64 + 32 + quad * 8];
    h8 bl0 = *(const h8*)&blp[kc * 64 + quad * 8];
    h8 bl1 = *(const h8*)&blp[kc * 64 + 32 + quad * 8];
    __syncthreads();
#pragma unroll
    for (int mf = 0; mf < 4; mf++) {
      h8 ah0 = *(const h8*)&Ah[mf * 16 + ln][quad * 8];
      h8 ah1 = *(const h8*)&Ah[mf * 16 + ln][32 + quad * 8];
      h8 al0 = *(const h8*)&Al[mf * 16 + ln][quad * 8];
      h8 al1 = *(const h8*)&Al[mf * 16 + ln][32 + quad * 8];
      mn[mf] = __builtin_amdgcn_mfma_f32_16x16x32_f16(ah0, bh0, mn[mf], 0, 0, 0);
      mn[mf] = __builtin_amdgcn_mfma_f32_16x16x32_f16(ah1, bh1, mn[mf], 0, 0, 0);
      cr[mf] = __builtin_amdgcn_mfma_f32_16x16x32_f16(ah0, bl0, cr[mf], 0, 0, 0);
      cr[mf] = __builtin_amdgcn_mfma_f32_16x16x32_f16(ah1, bl1, cr[mf], 0, 0, 0);
      cr[mf] = __builtin_amdgcn_mfma_f32_16x16x32_f16(al0, bh0, cr[mf], 0, 0, 0);
      cr[mf] = __builtin_amdgcn_mfma_f32_16x16x32_f16(al1, bh1, cr[mf], 0, 0, 0);
    }
    __syncthreads();
  }
#pragma unroll
  for (int mf = 0; mf < 4; mf++)
#pragma unroll
    for (int r = 0; r < 4; r++)
      cm[mf][r] = mn[mf][r] + cr[mf][r] * INV2048;
}

// ---------------------------------------------------------------------------
// QKV GEMM: q/k -> fp32 transposed [h*4+b][feat][s]; v -> bf16 hi/lo
// transposed [h*4+b][vcol][s]. grid (64 mt, 6 nt [0:q 1:k 2..5:v], 8 h)
// ---------------------------------------------------------------------------
__global__ __launch_bounds__(256) void k_mm_qkv(
    const float* __restrict__ net,
    const _Float16* __restrict__ wph, const _Float16* __restrict__ wpl,
    float* __restrict__ qtg, float* __restrict__ ktg,
    short* __restrict__ vth, short* __restrict__ vtl)
{
  __shared__ __align__(16) _Float16 Ah[64][LHS];
  __shared__ __align__(16) _Float16 Al[64][LHS];
  const int mt = blockIdx.x, nt = blockIdx.y, h = blockIdx.z;
  const int tid = threadIdx.x, wv = tid >> 6, lane = tid & 63;
  const int ln = lane & 15, quad = lane >> 4;
  const float* A = net + (size_t)h * 1048576 + (size_t)mt * 64 * 256;
  size_t bbase;
  if (nt == 0)      bbase = (size_t)h * 16384;
  else if (nt == 1) bbase = 131072 + (size_t)h * 16384;
  else              bbase = 262144 + (size_t)h * 65536 + (size_t)(nt - 2) * 64 * 256;
  f4 cm[4];
  mm_core(A, wph + bbase, wpl + bbase, cm, Ah, Al);

  if (nt <= 1) {
    float* dst = (nt == 0) ? qtg : ktg;
    int col = wv * 16 + ln;
#pragma unroll
    for (int mf = 0; mf < 4; mf++)
#pragma unroll
      for (int r = 0; r < 4; r++) {
        int row = mt * 64 + mf * 16 + quad * 4 + r;
        int b_ = row >> 10, sI = row & 1023;
        dst[((size_t)(h * 4 + b_) * 64 + col) * 1024 + sI] = cm[mf][r];
      }
  } else {
    int c = (nt - 2) * 64 + wv * 16 + ln;
#pragma unroll
    for (int mf = 0; mf < 4; mf++)
#pragma unroll
      for (int r = 0; r < 4; r++) {
        int row = mt * 64 + mf * 16 + quad * 4 + r;
        int b_ = row >> 10, sI = row & 1023;
        float v = cm[mf][r];
        short hi = f2bf(v);
        size_t idx = ((size_t)(h * 4 + b_) * 256 + c) * 1024 + sI;
        vth[idx] = hi;
        vtl[idx] = f2bf(v - bf2f(hi));
      }
  }
}

// ---------------------------------------------------------------------------
// Dense GEMM: tmp = net + relu(net @ Wd). grid (64 mt, 4 nt, 8 h)
// ---------------------------------------------------------------------------
__global__ __launch_bounds__(256) void k_mm_dense(
    const float* __restrict__ net,
    const _Float16* __restrict__ wph, const _Float16* __restrict__ wpl,
    float* __restrict__ tmp)
{
  __shared__ __align__(16) _Float16 Ah[64][LHS];
  __shared__ __align__(16) _Float16 Al[64][LHS];
  const int mt = blockIdx.x, nt = blockIdx.y, h = blockIdx.z;
  const int tid = threadIdx.x, wv = tid >> 6, lane = tid & 63;
  const int ln = lane & 15, quad = lane >> 4;
  const float* A = net + (size_t)h * 1048576 + (size_t)mt * 64 * 256;
  size_t bbase = 786432 + (size_t)h * 65536 + (size_t)nt * 64 * 256;
  f4 cm[4];
  mm_core(A, wph + bbase, wpl + bbase, cm, Ah, Al);

  int col = nt * 64 + wv * 16 + ln;
#pragma unroll
  for (int mf = 0; mf < 4; mf++)
#pragma unroll
    for (int r = 0; r < 4; r++) {
      int row = mt * 64 + mf * 16 + quad * 4 + r;
      size_t idx = (size_t)h * 1048576 + (size_t)row * 256 + col;
      tmp[idx] = net[idx] + fmaxf(cm[mf][r], 0.f);
    }
}

// ---------------------------------------------------------------------------
// Flash attention (R4 verbatim): fp32 QK^T + softmax, split-bf16 MFMA PV.
// grid (16 q-tiles, 4 batch, 8 heads)
// ---------------------------------------------------------------------------
__global__ __launch_bounds__(256, 2) void k_attn(
    const float* __restrict__ qtg, const float* __restrict__ ktg,
    const short* __restrict__ vth, const short* __restrict__ vtl,
    float* __restrict__ ob)
{
  __shared__ __align__(16) char smem[54272];
  float (*Qt)[LQP]  = (float(*)[LQP])(smem);            // 17,408 B
  float (*Ks)[LQP]  = (float(*)[LQP])(smem + 17408);    // 17,408 B (overlay)
  short (*Vh)[LKP]  = (short(*)[LKP])(smem + 17408);    //  9,216 B
  short (*Vl2)[LKP] = (short(*)[LKP])(smem + 26624);    //  9,216 B
  short (*Ph)[LKP]  = (short(*)[LKP])(smem + 35840);    //  9,216 B
  short (*Pl)[LKP]  = (short(*)[LKP])(smem + 45056);    //  9,216 B

  const int qt = blockIdx.x, b = blockIdx.y, h = blockIdx.z;
  const int tid = threadIdx.x;
  const int tx = tid & 15, ty = tid >> 4;
  const int wv = tid >> 6, lane = tid & 63, ln = lane & 15, quad = lane >> 4;
  const int hb = h * 4 + b;

  const float* qg  = qtg + (size_t)hb * 65536;   // [64 feat][1024 s]
  const float* kg  = ktg + (size_t)hb * 65536;
  const short* vhg = vth + (size_t)hb * 262144;  // [256 vcol][1024 s]
  const short* vlg = vtl + (size_t)hb * 262144;

#pragma unroll
  for (int i = 0; i < 4; i++) {
    int e = tid + i * 256;
    int f = e >> 4, c = e & 15;
    *(f4*)&Qt[f][c * 4] = *(const f4*)&qg[f * 1024 + qt * 64 + c * 4];
  }

  float m[4] = {-1e30f, -1e30f, -1e30f, -1e30f};
  float l[4] = {0.f, 0.f, 0.f, 0.f};
  f4 O[16];
#pragma unroll
  for (int nt = 0; nt < 16; nt++) O[nt] = (f4){0.f, 0.f, 0.f, 0.f};

  for (int kt = 0; kt < 16; kt++) {
#pragma unroll
    for (int i = 0; i < 4; i++) {
      int e = tid + i * 256;
      int f = e >> 4, c = e & 15;
      *(f4*)&Ks[f][c * 4] = *(const f4*)&kg[f * 1024 + kt * 64 + c * 4];
    }
    __syncthreads();   // B1

    float s[4][4];
#pragma unroll
    for (int i = 0; i < 4; i++)
#pragma unroll
      for (int j = 0; j < 4; j++) s[i][j] = 0.f;
#pragma unroll 16
    for (int kd = 0; kd < 64; kd++) {
      f4 aq = *(const f4*)&Qt[kd][ty * 4];
      f4 ak = *(const f4*)&Ks[kd][tx * 4];
#pragma unroll
      for (int i = 0; i < 4; i++)
#pragma unroll
        for (int j = 0; j < 4; j++)
          s[i][j] += aq[i] * ak[j];
    }

    float alpha[4];
#pragma unroll
    for (int i = 0; i < 4; i++) {
#pragma unroll
      for (int j = 0; j < 4; j++) s[i][j] *= SCL;
      float mloc = fmaxf(fmaxf(s[i][0], s[i][1]), fmaxf(s[i][2], s[i][3]));
#pragma unroll
      for (int d = 1; d < 16; d <<= 1)
        mloc = fmaxf(mloc, __shfl_xor(mloc, d, 64));
      float mnew = fmaxf(m[i], mloc);
      alpha[i] = __expf(m[i] - mnew);
      float ls = 0.f;
#pragma unroll
      for (int j = 0; j < 4; j++) { s[i][j] = __expf(s[i][j] - mnew); ls += s[i][j]; }
#pragma unroll
      for (int d = 1; d < 16; d <<= 1) ls += __shfl_xor(ls, d, 64);
      l[i] = l[i] * alpha[i] + ls;
      m[i] = mnew;
    }
#pragma unroll
    for (int nt = 0; nt < 16; nt++)
#pragma unroll
      for (int i = 0; i < 4; i++) O[nt][i] *= alpha[i];

#pragma unroll
    for (int i = 0; i < 4; i++) {
#pragma unroll
      for (int j = 0; j < 4; j++) {
        float p = s[i][j];
        short hi = f2bf(p);
        Ph[ty * 4 + i][tx * 4 + j] = hi;
        Pl[ty * 4 + i][tx * 4 + j] = f2bf(p - bf2f(hi));
      }
    }
    __syncthreads();   // B2

    bf8 ph0 = *(const bf8*)&Ph[wv * 16 + ln][quad * 8];
    bf8 ph1 = *(const bf8*)&Ph[wv * 16 + ln][32 + quad * 8];
    bf8 pl0 = *(const bf8*)&Pl[wv * 16 + ln][quad * 8];
    bf8 pl1 = *(const bf8*)&Pl[wv * 16 + ln][32 + quad * 8];

    for (int c4 = 0; c4 < 4; c4++) {
#pragma unroll
      for (int i = 0; i < 2; i++) {
        int e = tid + i * 256;
        int vc = e >> 3, fc = e & 7;
        size_t gidx = (size_t)(c4 * 64 + vc) * 1024 + kt * 64 + fc * 8;
        *(bf8*)&Vh[vc][fc * 8]  = *(const bf8*)&vhg[gidx];
        *(bf8*)&Vl2[vc][fc * 8] = *(const bf8*)&vlg[gidx];
      }
      __syncthreads();  // B3
#pragma unroll
      for (int n2 = 0; n2 < 4; n2++) {
        int nt = c4 * 4 + n2;
        bf8 vh0 = *(const bf8*)&Vh[n2 * 16 + ln][quad * 8];
        bf8 vh1 = *(const bf8*)&Vh[n2 * 16 + ln][32 + quad * 8];
        bf8 vl0 = *(const bf8*)&Vl2[n2 * 16 + ln][quad * 8];
        bf8 vl1 = *(const bf8*)&Vl2[n2 * 16 + ln][32 + quad * 8];
        O[nt] = __builtin_amdgcn_mfma_f32_16x16x32_bf16(ph0, vh0, O[nt], 0, 0, 0);
        O[nt] = __builtin_amdgcn_mfma_f32_16x16x32_bf16(ph1, vh1, O[nt], 0, 0, 0);
        O[nt] = __builtin_amdgcn_mfma_f32_16x16x32_bf16(ph0, vl0, O[nt], 0, 0, 0);
        O[nt] = __builtin_amdgcn_mfma_f32_16x16x32_bf16(ph1, vl1, O[nt], 0, 0, 0);
        O[nt] = __builtin_amdgcn_mfma_f32_16x16x32_bf16(pl0, vh0, O[nt], 0, 0, 0);
        O[nt] = __builtin_amdgcn_mfma_f32_16x16x32_bf16(pl1, vh1, O[nt], 0, 0, 0);
      }
      __syncthreads();  // B4
    }
  }

#pragma unroll
  for (int r = 0; r < 4; r++) {
    float linv = 1.f / l[r];
    int row = qt * 64 + ty * 4 + r;
    float* dst = ob + (size_t)h * 1048576 + (size_t)(b * 1024 + row) * 256;
#pragma unroll
    for (int nt = 0; nt < 16; nt++)
      dst[nt * 16 + ln] = O[nt][r] * linv;
  }
}

// ---------------------------------------------------------------------------
// BN stats (R4 verbatim)
// ---------------------------------------------------------------------------
__global__ __launch_bounds__(256) void k_bnstats(
    const float* __restrict__ a, const float* __restrict__ b,
    float* __restrict__ stats, int addB)
{
  const int h = blockIdx.y, r0 = blockIdx.x * 64, c = threadIdx.x;
  const float* pa = a + (size_t)h * 1048576 + r0 * 256 + c;
  float s = 0.f, s2 = 0.f;
  if (addB) {
    const float* pb = b + (size_t)h * 1048576 + r0 * 256 + c;
    for (int r = 0; r < 64; r++) {
      float y = pa[r * 256] + pb[r * 256];
      s += y; s2 += y * y;
    }
  } else {
    for (int r = 0; r < 64; r++) {
      float y = pa[r * 256];
      s += y; s2 += y * y;
    }
  }
  atomicAdd(&stats[(h * 256 + c) * 2], s);
  atomicAdd(&stats[(h * 256 + c) * 2 + 1], s2);
}

// ---------------------------------------------------------------------------
// BN apply (R4 verbatim)
// ---------------------------------------------------------------------------
__global__ __launch_bounds__(256) void k_bnapply(
    const float* __restrict__ a, const float* __restrict__ b,
    const float* __restrict__ stats,
    const float* __restrict__ gamma, const float* __restrict__ beta,
    float* __restrict__ dst, int t, int addB, int transposed)
{
  const int h = blockIdx.y, r0 = blockIdx.x * 64, c = threadIdx.x;
  float s  = stats[(h * 256 + c) * 2];
  float s2 = stats[(h * 256 + c) * 2 + 1];
  float mean = s * (1.f / 4096.f);
  float var  = s2 * (1.f / 4096.f) - mean * mean;
  float inv  = rsqrtf(var + EPSV);
  float g  = gamma[(h * TT + t) * 256 + c] * inv;
  float bt = beta[(h * TT + t) * 256 + c];
  const float* pa = a + (size_t)h * 1048576 + r0 * 256 + c;
  const float* pb = addB ? (b + (size_t)h * 1048576 + r0 * 256 + c) : nullptr;
  for (int r = 0; r < 64; r++) {
    float y = pa[r * 256];
    if (addB) y += pb[r * 256];
    float o = (y - mean) * g + bt;
    int rg = r0 + r;
    if (transposed) dst[((size_t)rg * HH + h) * 256 + c] = o;
    else            dst[(size_t)h * 1048576 + rg * 256 + c] = o;
  }
}

// ---------------------------------------------------------------------------
extern "C" void kernel_launch(void* const* d_in, const int* in_sizes, int n_in,
                              void* d_out, int out_size, void* d_ws, size_t ws_size,
                              hipStream_t stream)
{
  const float* x   = (const float*)d_in[0];
  const float* Win = (const float*)d_in[1];
  const float* Wq  = (const float*)d_in[2];
  const float* Wk  = (const float*)d_in[3];
  const float* Wv  = (const float*)d_in[4];
  const float* Wd  = (const float*)d_in[5];
  const float* g1  = (const float*)d_in[6];
  const float* b1  = (const float*)d_in[7];
  const float* g2  = (const float*)d_in[8];
  const float* b2  = (const float*)d_in[9];
  float* out = (float*)d_out;
  float* ws  = (float*)d_ws;

  float* net   = ws;                       // H*BS*V fp32       =  8,388,608 f
  float* tmp   = net + 8388608;            // H*BS*V fp32       =  8,388,608 f
  float* stats = tmp + 8388608;            // 8 phases * H*V*2  =     32,768 f
  float* qtg   = stats + 32768;            // H*B*KD*S fp32     =  2,097,152 f
  float* ktg   = qtg + 2097152;            // H*B*KD*S fp32     =  2,097,152 f
  short* vth   = (short*)(ktg + 2097152);  // H*B*V*S bf16 hi   =  8,388,608 s
  short* vtl   = vth + 8388608;            // H*B*V*S bf16 lo   =  8,388,608 s
  _Float16* wph = (_Float16*)(vtl + 8388608);  // prepped weights hi = 1,310,720 h
  _Float16* wpl = wph + 1310720;               // prepped weights lo = 1,310,720 h

  hipMemsetAsync(stats, 0, 8 * HH * VV * 2 * sizeof(float), stream);

  k_in_dense<<<dim3(64, 4), 256, 0, stream>>>(x, Win, net);

  for (int t = 0; t < TT; t++) {
    float* st1 = stats + (t * 2 + 0) * HH * VV * 2;
    float* st2 = stats + (t * 2 + 1) * HH * VV * 2;

    k_prep<<<dim3(10, 4, 8), 256, 0, stream>>>(Wq, Wk, Wv, Wd, wph, wpl, t);
    k_mm_qkv<<<dim3(64, 6, 8), 256, 0, stream>>>(net, wph, wpl, qtg, ktg, vth, vtl);
    k_attn<<<dim3(16, 4, 8), 256, 0, stream>>>(qtg, ktg, vth, vtl, tmp);

    k_bnstats<<<dim3(64, 8), 256, 0, stream>>>(net, tmp, st1, 1);
    k_bnapply<<<dim3(64, 8), 256, 0, stream>>>(net, tmp, st1, g1, b1, net, t, 1, 0);

    k_mm_dense<<<dim3(64, 4, 8), 256, 0, stream>>>(net, wph, wpl, tmp);

    k_bnstats<<<dim3(64, 8), 256, 0, stream>>>(tmp, nullptr, st2, 0);
    if (t < TT - 1)
      k_bnapply<<<dim3(64, 8), 256, 0, stream>>>(tmp, nullptr, st2, g2, b2, net, t, 0, 0);
    else
      k_bnapply<<<dim3(64, 8), 256, 0, stream>>>(tmp, nullptr, st2, g2, b2, out, t, 0, 1);
  }
}